// Round 6
// baseline (37929.376 us; speedup 1.0000x reference)
//
#include <hip/hip_runtime.h>
#include <hip/hip_bf16.h>

#define T_DIM 8192
#define O_DIM 1024
#define H_DIM 2048
#define G_DIM 6144   // 3*H
#define A_DIM 512
#define CHUNK 512    // steps per scan launch
#define NBLK 256     // scan blocks (1 per CU; forced by 104 KB LDS)

// ---- workspace layout (float offsets; total ~46.7 MB, proven safe) ----
#define OFF_GXC   0ull          // CHUNK x 3H fp32            (3,145,728 f)
#define OFF_HTAG  3145728ull    // 2 x H u64 {h,tag}          (8,192 f)
#define OFF_S     3153920ull    // 8192 scores fp32
#define OFF_RED   3162112ull    // max, sum (+pad)            (16 f)
#define OFF_CPART 3162128ull    // 64 x 2048 fp32             (131,072 f)
#define OFF_C     3293200ull    // 2048 fp32
#define OFF_HSBF  3295248ull    // T x H bf16                 (8,388,608 f)

__device__ __forceinline__ float bf2f(unsigned short u) {
  return __uint_as_float(((unsigned)u) << 16);
}

// ---------------- Phase 1: gx chunk = obs_chunk @ W_ih^T + b_ih ----------------
#define BM 64
#define BN 64
#define BK 16
__global__ __launch_bounds__(256) void gemm_gx(
    const float* __restrict__ A,   // CHUNK x O
    const float* __restrict__ B,   // 3H x O
    const float* __restrict__ bias,
    float* __restrict__ C) {       // CHUNK x 3H
  __shared__ float As[BM][BK + 1];
  __shared__ float Bs[BN][BK + 1];
  const int bm = blockIdx.x * BM;
  const int bn = blockIdx.y * BN;
  const int tid = threadIdx.x;
  const int tr = tid / 16, tc = tid % 16;
  float acc[4][4] = {};
  for (int k0 = 0; k0 < O_DIM; k0 += BK) {
    for (int i = tid; i < BM * BK; i += 256) {
      int r = i / BK, c = i % BK;
      As[r][c] = A[(size_t)(bm + r) * O_DIM + k0 + c];
    }
    for (int i = tid; i < BN * BK; i += 256) {
      int r = i / BK, c = i % BK;
      Bs[r][c] = B[(size_t)(bn + r) * O_DIM + k0 + c];
    }
    __syncthreads();
#pragma unroll
    for (int kk = 0; kk < BK; ++kk) {
      float a[4], b[4];
#pragma unroll
      for (int i = 0; i < 4; ++i) a[i] = As[tr * 4 + i][kk];
#pragma unroll
      for (int j = 0; j < 4; ++j) b[j] = Bs[tc * 4 + j][kk];
#pragma unroll
      for (int i = 0; i < 4; ++i)
#pragma unroll
        for (int j = 0; j < 4; ++j) acc[i][j] += a[i] * b[j];
    }
    __syncthreads();
  }
#pragma unroll
  for (int i = 0; i < 4; ++i)
#pragma unroll
    for (int j = 0; j < 4; ++j) {
      int r = bm + tr * 4 + i, cc = bn + tc * 4 + j;
      C[(size_t)r * G_DIM + cc] = acc[i][j] + bias[cc];
    }
}

// ---------------- Phase 2: persistent GRU scan, POLL-THE-DATA barrier ---------
// Each hidden unit is published as one 64-bit atomic word {f32 h | u32 tag}.
// Consumers poll slot[t&1] until every word's tag >= t, then use the h from the
// SAME word -> single IF round-trip replaces (flag store + flag poll + h load).
// Single-location atomicity => no fences needed at all. Ping-pong is safe: a
// producer writes tag t+1 only after observing all tags == t, i.e. after every
// block finished reading the slot it's about to overwrite (1-step lead bound).
__global__ __launch_bounds__(256, 1) void scan_chunk(
    const float* __restrict__ W_hh,        // 3H x H fp32
    const float* __restrict__ b_hh,        // 3H
    const float* __restrict__ gxc,         // CHUNK x 3H
    unsigned long long* __restrict__ htag, // 2 x H {h,tag}
    unsigned* __restrict__ hsbf,           // T x (H/2) packed bf16 pairs
    int t0, int nsteps) {
  __shared__ unsigned wlds[24][1024];  // 24 rows x 2048 bf16 (as 1024 uint) = 96 KB
  __shared__ float hlds[H_DIM];        // 8 KB
  const int tid = threadIdx.x;
  const int lane = tid & 63;
  const int wv = tid >> 6;             // wave 0..3
  const int blk = blockIdx.x;
  const int n0 = blk * 8 + wv * 2;     // first owned unit of this wave

  // ---- stage this block's 24 W_hh rows to LDS (bf16-packed), once/launch ----
  for (int i = tid; i < 24 * 1024; i += 256) {
    const int lr = i >> 10, c2 = i & 1023;
    const int lwv = lr / 6, rem = lr % 6;
    const int g = rem >> 1, o = rem & 1;
    const int row = g * H_DIM + blk * 8 + lwv * 2 + o;
    const float2 w2 = ((const float2*)(W_hh + (size_t)row * H_DIM))[c2];
    const unsigned u0 = (unsigned)__bfloat16_as_ushort(__float2bfloat16(w2.x));
    const unsigned u1 = (unsigned)__bfloat16_as_ushort(__float2bfloat16(w2.y));
    wlds[lr][c2] = (u1 << 16) | u0;
  }

  // ---- owner-lane constants (lanes 0,1 own n0, n0+1) ----
  float b0 = 0.f, b1 = 0.f, b2 = 0.f;
  const int nown = n0 + lane;
  if (lane < 2) {
    b0 = b_hh[nown];
    b1 = b_hh[H_DIM + nown];
    b2 = b_hh[2 * H_DIM + nown];
  }

  for (int tt = 0; tt < nsteps; ++tt) {
    const int t = t0 + tt;
    const unsigned long long* hin = htag + (size_t)(t & 1) * H_DIM;
    unsigned long long* hout = htag + (size_t)((t + 1) & 1) * H_DIM;

    // gx for owner lanes (independent; hides under poll)
    float gx0 = 0.f, gx1 = 0.f, gx2 = 0.f;
    if (lane < 2) {
      const float* g = gxc + (size_t)tt * G_DIM + nown;
      gx0 = g[0]; gx1 = g[H_DIM]; gx2 = g[2 * H_DIM];
    }

    __syncthreads();   // previous step's hlds readers are done (also: wlds ready at tt=0)

    // ---- poll-the-data: 8 units/thread, coalesced; tag and h in one word ----
    unsigned long long v[8];
    const unsigned tgt = (unsigned)t;
    for (;;) {
      bool ok = true;
#pragma unroll
      for (int j = 0; j < 8; ++j) {
        v[j] = __hip_atomic_load(hin + tid + 256 * j,
                                 __ATOMIC_RELAXED, __HIP_MEMORY_SCOPE_AGENT);
        ok = ok && ((unsigned)v[j] >= tgt);
      }
      if (ok) break;
      __builtin_amdgcn_s_sleep(1);
    }
#pragma unroll
    for (int j = 0; j < 8; ++j)
      hlds[tid + 256 * j] = __uint_as_float((unsigned)(v[j] >> 32));
    __syncthreads();   // hlds ready

    // ---- 6 dot products vs LDS weights: lane handles 4 chunks of 8 cols ----
    float acc[6] = {0.f, 0.f, 0.f, 0.f, 0.f, 0.f};
    const float4* h4 = (const float4*)hlds;
#pragma unroll
    for (int kp = 0; kp < 4; ++kp) {
      const int cb = lane + 64 * kp;          // 8-col chunk id (cols 8cb..8cb+7)
      const float4 ha = h4[2 * cb];
      const float4 hb = h4[2 * cb + 1];
#pragma unroll
      for (int r = 0; r < 6; ++r) {
        const uint4 wu = ((const uint4*)&wlds[wv * 6 + r][0])[cb];
        acc[r] += __uint_as_float(wu.x << 16) * ha.x
                + __uint_as_float(wu.x & 0xffff0000u) * ha.y
                + __uint_as_float(wu.y << 16) * ha.z
                + __uint_as_float(wu.y & 0xffff0000u) * ha.w
                + __uint_as_float(wu.z << 16) * hb.x
                + __uint_as_float(wu.z & 0xffff0000u) * hb.y
                + __uint_as_float(wu.w << 16) * hb.z
                + __uint_as_float(wu.w & 0xffff0000u) * hb.w;
      }
    }
#pragma unroll
    for (int r = 0; r < 6; ++r) {
#pragma unroll
      for (int d = 32; d > 0; d >>= 1) acc[r] += __shfl_xor(acc[r], d, 64);
    }

    // ---- gates on owner lanes; publish {h, tag} as one atomic word ----
    float hnew = 0.f;
    if (lane < 2) {
      const float rr = 1.f / (1.f + expf(-(gx0 + acc[0 + lane] + b0)));
      const float zz = 1.f / (1.f + expf(-(gx1 + acc[2 + lane] + b1)));
      const float nn = tanhf(gx2 + rr * (acc[4 + lane] + b2));
      hnew = (1.f - zz) * nn + zz * hlds[nown];
      const unsigned long long pk =
          ((unsigned long long)__float_as_uint(hnew) << 32) |
          (unsigned long long)(unsigned)(t + 1);
      __hip_atomic_store(hout + nown, pk,
                         __ATOMIC_RELAXED, __HIP_MEMORY_SCOPE_AGENT);
    }
    const float h1 = __shfl(hnew, 1, 64);
    if (lane == 0) {
      const unsigned u0 = (unsigned)__bfloat16_as_ushort(__float2bfloat16(hnew));
      const unsigned u1 = (unsigned)__bfloat16_as_ushort(__float2bfloat16(h1));
      hsbf[(size_t)t * (H_DIM / 2) + (blk * 4 + wv)] = (u1 << 16) | u0;
    }
  }
}

// ---------------- Phase 3a: attention scores (bf16 h_mid, h_last from htag) ---
__global__ __launch_bounds__(256) void attn_scores(
    const unsigned short* __restrict__ hs_bf,
    const unsigned long long* __restrict__ hq,  // slot0 of htag: {h,tag=8192}
    float* __restrict__ s, int n) {
  __shared__ float hl[H_DIM];
  const int tid = threadIdx.x;
  for (int i = tid; i < H_DIM; i += 256)
    hl[i] = __uint_as_float((unsigned)(hq[i] >> 32));
  __syncthreads();
  const int wave = tid >> 6, lane = tid & 63;
  const int t = blockIdx.x * 4 + wave;
  if (t >= n) return;
  const uint4* r4 = (const uint4*)(hs_bf + (size_t)t * H_DIM);
  float sum = 0.f;
#pragma unroll
  for (int u = 0; u < 4; ++u) {
    const int idx = lane + 64 * u;
    uint4 v = r4[idx];
    const float* l = hl + idx * 8;
    sum += bf2f((unsigned short)(v.x & 0xffff)) * l[0];
    sum += bf2f((unsigned short)(v.x >> 16))    * l[1];
    sum += bf2f((unsigned short)(v.y & 0xffff)) * l[2];
    sum += bf2f((unsigned short)(v.y >> 16))    * l[3];
    sum += bf2f((unsigned short)(v.z & 0xffff)) * l[4];
    sum += bf2f((unsigned short)(v.z >> 16))    * l[5];
    sum += bf2f((unsigned short)(v.w & 0xffff)) * l[6];
    sum += bf2f((unsigned short)(v.w >> 16))    * l[7];
  }
#pragma unroll
  for (int d = 32; d > 0; d >>= 1) sum += __shfl_xor(sum, d, 64);
  if (lane == 0) s[t] = sum;
}

// ---------------- Phase 3b: softmax stats ----------------
__global__ __launch_bounds__(1024) void softmax_stats(
    const float* __restrict__ s, int n, float* __restrict__ red) {
  __shared__ float buf[1024];
  const int tid = threadIdx.x;
  float m = -3.4e38f;
  for (int i = tid; i < n; i += 1024) m = fmaxf(m, s[i]);
  buf[tid] = m;
  __syncthreads();
  for (int d = 512; d > 0; d >>= 1) {
    if (tid < d) buf[tid] = fmaxf(buf[tid], buf[tid + d]);
    __syncthreads();
  }
  const float mm = buf[0];
  __syncthreads();
  float sum = 0.f;
  for (int i = tid; i < n; i += 1024) sum += expf(s[i] - mm);
  buf[tid] = sum;
  __syncthreads();
  for (int d = 512; d > 0; d >>= 1) {
    if (tid < d) buf[tid] += buf[tid + d];
    __syncthreads();
  }
  if (tid == 0) { red[0] = mm; red[1] = buf[0]; }
}

// ---------------- Phase 3c: weighted sum partials (bf16 h_mid) ----------------
__global__ __launch_bounds__(256) void attn_wsum(
    const unsigned short* __restrict__ hs_bf, const float* __restrict__ s,
    const float* __restrict__ red, float* __restrict__ c_part, int n) {
  const int tid = threadIdx.x;
  const float m = red[0];
  const float inv = 1.f / red[1];
  const int tchunk = (n + 63) / 64;
  const int t0 = blockIdx.x * tchunk;
  const int t1 = min(t0 + tchunk, n);
  float acc[8] = {};
  for (int t = t0; t < t1; ++t) {
    const float w = expf(s[t] - m) * inv;
    const uint4 v = ((const uint4*)(hs_bf + (size_t)t * H_DIM))[tid];
    acc[0] += w * bf2f((unsigned short)(v.x & 0xffff));
    acc[1] += w * bf2f((unsigned short)(v.x >> 16));
    acc[2] += w * bf2f((unsigned short)(v.y & 0xffff));
    acc[3] += w * bf2f((unsigned short)(v.y >> 16));
    acc[4] += w * bf2f((unsigned short)(v.z & 0xffff));
    acc[5] += w * bf2f((unsigned short)(v.z >> 16));
    acc[6] += w * bf2f((unsigned short)(v.w & 0xffff));
    acc[7] += w * bf2f((unsigned short)(v.w >> 16));
  }
  float* dst = c_part + (size_t)blockIdx.x * H_DIM + tid * 8;
#pragma unroll
  for (int k = 0; k < 8; ++k) dst[k] = acc[k];
}

// ---------------- Phase 3d: reduce partials ----------------
__global__ __launch_bounds__(256) void reduce_c(
    const float* __restrict__ c_part, float* __restrict__ c) {
  const int i = blockIdx.x * 256 + threadIdx.x;
  float sum = 0.f;
  for (int b = 0; b < 64; ++b) sum += c_part[(size_t)b * H_DIM + i];
  c[i] = sum;
}

// ---------------- Phase 3e: output heads ----------------
__global__ __launch_bounds__(64) void logits_kernel(
    const float* __restrict__ W_o, const float* __restrict__ b_o,
    const float* __restrict__ W_d, const float* __restrict__ b_d,
    const float* __restrict__ c, float* __restrict__ out) {
  const int j = blockIdx.x;
  const int lane = threadIdx.x;
  const float* W; const float* bb; int jj;
  if (j < A_DIM) { W = W_o; bb = b_o; jj = j; }
  else { W = W_d; bb = b_d; jj = j - A_DIM; }
  const float4* w4 = (const float4*)(W + (size_t)jj * H_DIM);
  const float4* c4 = (const float4*)c;
  float sum = 0.f;
#pragma unroll
  for (int u = 0; u < 8; ++u) {
    float4 a = w4[lane + 64 * u];
    float4 b = c4[lane + 64 * u];
    sum += a.x * b.x + a.y * b.y + a.z * b.z + a.w * b.w;
  }
#pragma unroll
  for (int d = 32; d > 0; d >>= 1) sum += __shfl_xor(sum, d, 64);
  if (lane == 0) out[j] = sum + bb[jj];
}

extern "C" void kernel_launch(void* const* d_in, const int* in_sizes, int n_in,
                              void* d_out, int out_size, void* d_ws, size_t ws_size,
                              hipStream_t stream) {
  const float* obs  = (const float*)d_in[0];
  const float* W_ih = (const float*)d_in[1];
  const float* W_hh = (const float*)d_in[2];
  const float* b_ih = (const float*)d_in[3];
  const float* b_hh = (const float*)d_in[4];
  const float* W_o  = (const float*)d_in[5];
  const float* b_o  = (const float*)d_in[6];
  const float* W_d  = (const float*)d_in[7];
  const float* b_d  = (const float*)d_in[8];
  float* out = (float*)d_out;
  float* ws = (float*)d_ws;

  float* gxc      = ws + OFF_GXC;
  unsigned long long* htag = (unsigned long long*)(ws + OFF_HTAG);
  float* s        = ws + OFF_S;
  float* red      = ws + OFF_RED;
  float* c_part   = ws + OFF_CPART;
  float* c        = ws + OFF_C;
  unsigned* hsbf  = (unsigned*)(ws + OFF_HSBF);

  // slot0 = {h=0, tag=0} for all units -> valid input for step t=0
  hipMemsetAsync(htag, 0, 2 * H_DIM * sizeof(unsigned long long), stream);

  for (int ci = 0; ci < T_DIM / CHUNK; ++ci) {
    gemm_gx<<<dim3(CHUNK / BM, G_DIM / BN), 256, 0, stream>>>(
        obs + (size_t)ci * CHUNK * O_DIM, W_ih, b_ih, gxc);
    scan_chunk<<<NBLK, 256, 0, stream>>>(
        W_hh, b_hh, gxc, htag, hsbf, ci * CHUNK, CHUNK);
  }
  // final h (tag 8192, even) is in htag slot 0
  const unsigned long long* h_last = htag;

  const int n = T_DIM - 1;  // 8191 mid states
  attn_scores<<<(n + 3) / 4, 256, 0, stream>>>(
      (const unsigned short*)hsbf, h_last, s, n);
  softmax_stats<<<1, 1024, 0, stream>>>(s, n, red);
  attn_wsum<<<64, 256, 0, stream>>>((const unsigned short*)hsbf, s, red, c_part, n);
  reduce_c<<<H_DIM / 256, 256, 0, stream>>>(c_part, c);
  logits_kernel<<<2 * A_DIM, 64, 0, stream>>>(W_o, b_o, W_d, b_d, c, out);
}

// Round 7
// 35228.680 us; speedup vs baseline: 1.0767x; 1.0767x over previous
//
#include <hip/hip_runtime.h>
#include <hip/hip_bf16.h>

#define T_DIM 8192
#define O_DIM 1024
#define H_DIM 2048
#define G_DIM 6144   // 3*H
#define A_DIM 512
#define CHUNK 512    // steps per scan launch
#define NBLK 256     // scan blocks (1 per CU; forced by dummy LDS)

// ---- workspace layout (float offsets; total ~46.7 MB, proven safe) ----
#define OFF_GXC   0ull          // CHUNK x 3H fp32            (3,145,728 f)
#define OFF_HTAG  3145728ull    // 2 x H u64 {h,tag}          (8,192 f)
#define OFF_S     3153920ull    // 8192 scores fp32
#define OFF_RED   3162112ull    // max, sum (+pad)            (16 f)
#define OFF_CPART 3162128ull    // 64 x 2048 fp32             (131,072 f)
#define OFF_C     3293200ull    // 2048 fp32
#define OFF_HSBF  3295248ull    // T x H bf16                 (8,388,608 f)

__device__ __forceinline__ float bf2f(unsigned short u) {
  return __uint_as_float(((unsigned)u) << 16);
}

// ---------------- Phase 1: gx chunk = obs_chunk @ W_ih^T + b_ih ----------------
#define BM 64
#define BN 64
#define BK 16
__global__ __launch_bounds__(256) void gemm_gx(
    const float* __restrict__ A,   // CHUNK x O
    const float* __restrict__ B,   // 3H x O
    const float* __restrict__ bias,
    float* __restrict__ C) {       // CHUNK x 3H
  __shared__ float As[BM][BK + 1];
  __shared__ float Bs[BN][BK + 1];
  const int bm = blockIdx.x * BM;
  const int bn = blockIdx.y * BN;
  const int tid = threadIdx.x;
  const int tr = tid / 16, tc = tid % 16;
  float acc[4][4] = {};
  for (int k0 = 0; k0 < O_DIM; k0 += BK) {
    for (int i = tid; i < BM * BK; i += 256) {
      int r = i / BK, c = i % BK;
      As[r][c] = A[(size_t)(bm + r) * O_DIM + k0 + c];
    }
    for (int i = tid; i < BN * BK; i += 256) {
      int r = i / BK, c = i % BK;
      Bs[r][c] = B[(size_t)(bn + r) * O_DIM + k0 + c];
    }
    __syncthreads();
#pragma unroll
    for (int kk = 0; kk < BK; ++kk) {
      float a[4], b[4];
#pragma unroll
      for (int i = 0; i < 4; ++i) a[i] = As[tr * 4 + i][kk];
#pragma unroll
      for (int j = 0; j < 4; ++j) b[j] = Bs[tc * 4 + j][kk];
#pragma unroll
      for (int i = 0; i < 4; ++i)
#pragma unroll
        for (int j = 0; j < 4; ++j) acc[i][j] += a[i] * b[j];
    }
    __syncthreads();
  }
#pragma unroll
  for (int i = 0; i < 4; ++i)
#pragma unroll
    for (int j = 0; j < 4; ++j) {
      int r = bm + tr * 4 + i, cc = bn + tc * 4 + j;
      C[(size_t)r * G_DIM + cc] = acc[i][j] + bias[cc];
    }
}

// ---------------- Phase 2: persistent GRU scan -------------------------------
// 256 blocks x 512 threads (8 waves). Wave wv owns unit u = blk*8+wv; its 3
// W_hh rows live in VGPRs as fp32 (lane l holds cols {4l..4l+3}+256j, j=0..7
// => float4 warr[3][8] = 96 VGPRs, statically indexed). Cross-block exchange
// via poll-the-data u64 {f32 h | u32 tag} words at agent scope (IF-served,
// fence-free). Dummy LDS forces 1 block/CU so no CU runs 2 blocks (a 2x-slow
// block would gate the whole grid every step).
__global__ __launch_bounds__(512, 2) void scan_chunk(
    const float* __restrict__ W_hh,        // 3H x H fp32
    const float* __restrict__ b_hh,        // 3H
    const float* __restrict__ gxc,         // CHUNK x 3H
    unsigned long long* __restrict__ htag, // 2 x H {h,tag}
    unsigned short* __restrict__ hsbf16,   // T x H bf16
    int t0, int nsteps) {
  __shared__ char smem[98304];             // 96 KB: h-stage + exclusivity pad
  float* hlds = (float*)smem;              // H_DIM floats (8 KB used)
  const int tid = threadIdx.x;
  const int lane = tid & 63;
  const int wv = tid >> 6;                 // wave 0..7
  const int blk = blockIdx.x;
  const int u = blk * 8 + wv;              // owned unit

  // ---- weights to VGPRs (once per launch), fp32 ----
  float4 warr[3][8];
#pragma unroll
  for (int g = 0; g < 3; ++g) {
    const float4* wrow = (const float4*)(W_hh + (size_t)(g * H_DIM + u) * H_DIM);
#pragma unroll
    for (int j = 0; j < 8; ++j) warr[g][j] = wrow[lane + 64 * j];
  }
  float b0 = 0.f, b1 = 0.f, b2 = 0.f;
  if (lane == 0) {
    b0 = b_hh[u]; b1 = b_hh[H_DIM + u]; b2 = b_hh[2 * H_DIM + u];
  }

  for (int tt = 0; tt < nsteps; ++tt) {
    const int t = t0 + tt;
    const unsigned long long* hin = htag + (size_t)(t & 1) * H_DIM;
    unsigned long long* hout = htag + (size_t)((t + 1) & 1) * H_DIM;

    // gx for owner lane (independent; latency hides under poll)
    float gx0 = 0.f, gx1 = 0.f, gx2 = 0.f;
    if (lane == 0) {
      const float* g = gxc + (size_t)tt * G_DIM + u;
      gx0 = g[0]; gx1 = g[H_DIM]; gx2 = g[2 * H_DIM];
    }

    __syncthreads();   // previous step's hlds readers are done

    // ---- poll-the-data: 4 u64/thread, coalesced ----
    unsigned long long v[4];
    const unsigned tgt = (unsigned)t;
    for (;;) {
      bool ok = true;
#pragma unroll
      for (int j = 0; j < 4; ++j) {
        v[j] = __hip_atomic_load(hin + tid + 512 * j,
                                 __ATOMIC_RELAXED, __HIP_MEMORY_SCOPE_AGENT);
        ok = ok && ((unsigned)v[j] >= tgt);
      }
      if (ok) break;
      __builtin_amdgcn_s_sleep(1);
    }
#pragma unroll
    for (int j = 0; j < 4; ++j)
      hlds[tid + 512 * j] = __uint_as_float((unsigned)(v[j] >> 32));
    __syncthreads();   // hlds ready

    // ---- 3 dot products off register weights ----
    float a0 = 0.f, a1 = 0.f, a2 = 0.f;
    const float4* h4 = (const float4*)hlds;
#pragma unroll
    for (int j = 0; j < 8; ++j) {
      const float4 h = h4[lane + 64 * j];
      a0 += warr[0][j].x * h.x + warr[0][j].y * h.y
          + warr[0][j].z * h.z + warr[0][j].w * h.w;
      a1 += warr[1][j].x * h.x + warr[1][j].y * h.y
          + warr[1][j].z * h.z + warr[1][j].w * h.w;
      a2 += warr[2][j].x * h.x + warr[2][j].y * h.y
          + warr[2][j].z * h.z + warr[2][j].w * h.w;
    }
#pragma unroll
    for (int d = 32; d > 0; d >>= 1) {
      a0 += __shfl_xor(a0, d, 64);
      a1 += __shfl_xor(a1, d, 64);
      a2 += __shfl_xor(a2, d, 64);
    }

    // ---- gates + publish on owner lane ----
    if (lane == 0) {
      const float rr = 1.f / (1.f + expf(-(gx0 + a0 + b0)));
      const float zz = 1.f / (1.f + expf(-(gx1 + a1 + b1)));
      const float nn = tanhf(gx2 + rr * (a2 + b2));
      const float hnew = (1.f - zz) * nn + zz * hlds[u];
      const unsigned long long pk =
          ((unsigned long long)__float_as_uint(hnew) << 32) |
          (unsigned long long)(unsigned)(t + 1);
      __hip_atomic_store(hout + u, pk,
                         __ATOMIC_RELAXED, __HIP_MEMORY_SCOPE_AGENT);
      hsbf16[(size_t)t * H_DIM + u] =
          (unsigned short)__bfloat16_as_ushort(__float2bfloat16(hnew));
    }
  }
}

// ---------------- Phase 3a: attention scores (bf16 h_mid, h_last from htag) ---
__global__ __launch_bounds__(256) void attn_scores(
    const unsigned short* __restrict__ hs_bf,
    const unsigned long long* __restrict__ hq,  // slot0 of htag: {h,tag=8192}
    float* __restrict__ s, int n) {
  __shared__ float hl[H_DIM];
  const int tid = threadIdx.x;
  for (int i = tid; i < H_DIM; i += 256)
    hl[i] = __uint_as_float((unsigned)(hq[i] >> 32));
  __syncthreads();
  const int wave = tid >> 6, lane = tid & 63;
  const int t = blockIdx.x * 4 + wave;
  if (t >= n) return;
  const uint4* r4 = (const uint4*)(hs_bf + (size_t)t * H_DIM);
  float sum = 0.f;
#pragma unroll
  for (int u = 0; u < 4; ++u) {
    const int idx = lane + 64 * u;
    uint4 v = r4[idx];
    const float* l = hl + idx * 8;
    sum += bf2f((unsigned short)(v.x & 0xffff)) * l[0];
    sum += bf2f((unsigned short)(v.x >> 16))    * l[1];
    sum += bf2f((unsigned short)(v.y & 0xffff)) * l[2];
    sum += bf2f((unsigned short)(v.y >> 16))    * l[3];
    sum += bf2f((unsigned short)(v.z & 0xffff)) * l[4];
    sum += bf2f((unsigned short)(v.z >> 16))    * l[5];
    sum += bf2f((unsigned short)(v.w & 0xffff)) * l[6];
    sum += bf2f((unsigned short)(v.w >> 16))    * l[7];
  }
#pragma unroll
  for (int d = 32; d > 0; d >>= 1) sum += __shfl_xor(sum, d, 64);
  if (lane == 0) s[t] = sum;
}

// ---------------- Phase 3b: softmax stats ----------------
__global__ __launch_bounds__(1024) void softmax_stats(
    const float* __restrict__ s, int n, float* __restrict__ red) {
  __shared__ float buf[1024];
  const int tid = threadIdx.x;
  float m = -3.4e38f;
  for (int i = tid; i < n; i += 1024) m = fmaxf(m, s[i]);
  buf[tid] = m;
  __syncthreads();
  for (int d = 512; d > 0; d >>= 1) {
    if (tid < d) buf[tid] = fmaxf(buf[tid], buf[tid + d]);
    __syncthreads();
  }
  const float mm = buf[0];
  __syncthreads();
  float sum = 0.f;
  for (int i = tid; i < n; i += 1024) sum += expf(s[i] - mm);
  buf[tid] = sum;
  __syncthreads();
  for (int d = 512; d > 0; d >>= 1) {
    if (tid < d) buf[tid] += buf[tid + d];
    __syncthreads();
  }
  if (tid == 0) { red[0] = mm; red[1] = buf[0]; }
}

// ---------------- Phase 3c: weighted sum partials (bf16 h_mid) ----------------
__global__ __launch_bounds__(256) void attn_wsum(
    const unsigned short* __restrict__ hs_bf, const float* __restrict__ s,
    const float* __restrict__ red, float* __restrict__ c_part, int n) {
  const int tid = threadIdx.x;
  const float m = red[0];
  const float inv = 1.f / red[1];
  const int tchunk = (n + 63) / 64;
  const int t0 = blockIdx.x * tchunk;
  const int t1 = min(t0 + tchunk, n);
  float acc[8] = {};
  for (int t = t0; t < t1; ++t) {
    const float w = expf(s[t] - m) * inv;
    const uint4 v = ((const uint4*)(hs_bf + (size_t)t * H_DIM))[tid];
    acc[0] += w * bf2f((unsigned short)(v.x & 0xffff));
    acc[1] += w * bf2f((unsigned short)(v.x >> 16));
    acc[2] += w * bf2f((unsigned short)(v.y & 0xffff));
    acc[3] += w * bf2f((unsigned short)(v.y >> 16));
    acc[4] += w * bf2f((unsigned short)(v.z & 0xffff));
    acc[5] += w * bf2f((unsigned short)(v.z >> 16));
    acc[6] += w * bf2f((unsigned short)(v.w & 0xffff));
    acc[7] += w * bf2f((unsigned short)(v.w >> 16));
  }
  float* dst = c_part + (size_t)blockIdx.x * H_DIM + tid * 8;
#pragma unroll
  for (int k = 0; k < 8; ++k) dst[k] = acc[k];
}

// ---------------- Phase 3d: reduce partials ----------------
__global__ __launch_bounds__(256) void reduce_c(
    const float* __restrict__ c_part, float* __restrict__ c) {
  const int i = blockIdx.x * 256 + threadIdx.x;
  float sum = 0.f;
  for (int b = 0; b < 64; ++b) sum += c_part[(size_t)b * H_DIM + i];
  c[i] = sum;
}

// ---------------- Phase 3e: output heads ----------------
__global__ __launch_bounds__(64) void logits_kernel(
    const float* __restrict__ W_o, const float* __restrict__ b_o,
    const float* __restrict__ W_d, const float* __restrict__ b_d,
    const float* __restrict__ c, float* __restrict__ out) {
  const int j = blockIdx.x;
  const int lane = threadIdx.x;
  const float* W; const float* bb; int jj;
  if (j < A_DIM) { W = W_o; bb = b_o; jj = j; }
  else { W = W_d; bb = b_d; jj = j - A_DIM; }
  const float4* w4 = (const float4*)(W + (size_t)jj * H_DIM);
  const float4* c4 = (const float4*)c;
  float sum = 0.f;
#pragma unroll
  for (int u = 0; u < 8; ++u) {
    float4 a = w4[lane + 64 * u];
    float4 b = c4[lane + 64 * u];
    sum += a.x * b.x + a.y * b.y + a.z * b.z + a.w * b.w;
  }
#pragma unroll
  for (int d = 32; d > 0; d >>= 1) sum += __shfl_xor(sum, d, 64);
  if (lane == 0) out[j] = sum + bb[jj];
}

extern "C" void kernel_launch(void* const* d_in, const int* in_sizes, int n_in,
                              void* d_out, int out_size, void* d_ws, size_t ws_size,
                              hipStream_t stream) {
  const float* obs  = (const float*)d_in[0];
  const float* W_ih = (const float*)d_in[1];
  const float* W_hh = (const float*)d_in[2];
  const float* b_ih = (const float*)d_in[3];
  const float* b_hh = (const float*)d_in[4];
  const float* W_o  = (const float*)d_in[5];
  const float* b_o  = (const float*)d_in[6];
  const float* W_d  = (const float*)d_in[7];
  const float* b_d  = (const float*)d_in[8];
  float* out = (float*)d_out;
  float* ws = (float*)d_ws;

  float* gxc      = ws + OFF_GXC;
  unsigned long long* htag = (unsigned long long*)(ws + OFF_HTAG);
  float* s        = ws + OFF_S;
  float* red      = ws + OFF_RED;
  float* c_part   = ws + OFF_CPART;
  float* c        = ws + OFF_C;
  unsigned short* hsbf16 = (unsigned short*)(ws + OFF_HSBF);

  // slot0 = {h=0, tag=0} for all units -> valid input for step t=0
  hipMemsetAsync(htag, 0, 2 * H_DIM * sizeof(unsigned long long), stream);

  for (int ci = 0; ci < T_DIM / CHUNK; ++ci) {
    gemm_gx<<<dim3(CHUNK / BM, G_DIM / BN), 256, 0, stream>>>(
        obs + (size_t)ci * CHUNK * O_DIM, W_ih, b_ih, gxc);
    scan_chunk<<<NBLK, 512, 0, stream>>>(
        W_hh, b_hh, gxc, htag, hsbf16, ci * CHUNK, CHUNK);
  }
  // final h (tag 8192, even) is in htag slot 0
  const unsigned long long* h_last = htag;

  const int n = T_DIM - 1;  // 8191 mid states
  attn_scores<<<(n + 3) / 4, 256, 0, stream>>>(hsbf16, h_last, s, n);
  softmax_stats<<<1, 1024, 0, stream>>>(s, n, red);
  attn_wsum<<<64, 256, 0, stream>>>(hsbf16, s, red, c_part, n);
  reduce_c<<<H_DIM / 256, 256, 0, stream>>>(c_part, c);
  logits_kernel<<<2 * A_DIM, 64, 0, stream>>>(W_o, b_o, W_d, b_d, c, out);
}